// Round 5
// baseline (599.237 us; speedup 1.0000x reference)
//
#include <hip/hip_runtime.h>

#define N_NODES 50000
#define NEDGE   800000
#define HID     128
#define LDSP    129          // doubles per LDS row (fp64 repair kernel)
#define TAU     2.5e-7       // flag margin: must exceed 1e-7 ref-slack + 2*dy
#define GRID_A  2048         // persistent blocks for edgeA (grid-stride)

// ---- workspace layout (units: doubles) ----
#define W1D_OFF 0            // 257*128 = 32896, row-major [k][j]
#define B1D_OFF 32896        // 128
#define W2D_OFF 33024        // 128*128 = 16384
#define B2D_OFF 49408        // 128
#define W3D_OFF 49536        // 128
#define B3D_OFF 49664        // 1
#define NWCONV  49665
#define PQ64_OFF 49672                                        // P64,Q64: each N*128 doubles
#define P32_OFF_D  (PQ64_OFF + 2ull * N_NODES * HID)          // P32,Q32 floats overlay
#define FLAG_OFF_D (P32_OFF_D + 1ull * N_NODES * HID)         // int cnt + int list[N]
#define Z_OFF_D    (FLAG_OFF_D + 25008)                       // z[NEDGE] doubles
#define W2THI_OFF_D (Z_OFF_D + NEDGE)                         // W2^T bf16 hi [j][k] 16384 shorts
#define W2TLO_OFF_D (W2THI_OFF_D + 4096)                      // W2^T bf16 lo
// total ~161 MB < 256 MiB workspace

typedef __attribute__((ext_vector_type(8)))  short short8;
typedef __attribute__((ext_vector_type(16))) float f32x16;

__device__ __forceinline__ unsigned short f2bf(float f) {
    const unsigned u = __float_as_uint(f);
    const unsigned r = u + 0x7FFFu + ((u >> 16) & 1u);   // RN-even; inputs finite
    return (unsigned short)(r >> 16);
}
__device__ __forceinline__ float bf2f(unsigned short h) {
    return __uint_as_float((unsigned)h << 16);
}

// ---------------------------------------------------------------------------
// Kernel 0: convert weights to fp64 (for exact repair path) + W2^T bf16 hi/lo
// (for the MFMA fast pass); zero the flagged-node counter.
// ---------------------------------------------------------------------------
__global__ void conv_kernel(const float* __restrict__ w1, const float* __restrict__ b1,
                            const float* __restrict__ w2, const float* __restrict__ b2,
                            const float* __restrict__ w3, const float* __restrict__ b3,
                            double* __restrict__ wsd) {
    const int i = blockIdx.x * 256 + threadIdx.x;
    if (i == 0) *(int*)(wsd + FLAG_OFF_D) = 0;
    if (i < 16384) {                       // W2^T split: [j][k] from w2[k][j]
        const int k = i >> 7, j = i & 127;
        const float v = w2[i];
        const unsigned short hi = f2bf(v);
        const unsigned short lo = f2bf(v - bf2f(hi));
        short* w2thi = (short*)(wsd + W2THI_OFF_D);
        short* w2tlo = (short*)(wsd + W2TLO_OFF_D);
        w2thi[j * 128 + k] = (short)hi;
        w2tlo[j * 128 + k] = (short)lo;
    }
    if (i >= NWCONV) return;
    float v;
    if      (i < B1D_OFF) v = w1[i];
    else if (i < W2D_OFF) v = b1[i - B1D_OFF];
    else if (i < B2D_OFF) v = w2[i - W2D_OFF];
    else if (i < W3D_OFF) v = b2[i - B2D_OFF];
    else if (i < B3D_OFF) v = w3[i - W3D_OFF];
    else                  v = b3[0];
    wsd[i] = (double)v;
}

// ---------------------------------------------------------------------------
// Kernel 1: P[n][j] = sum_k f[n][k] w1[k][j] (sel=0), Q with rows 128..255.
// fp64 accumulate; also writes fp32 copies for the fast pass. (unchanged)
// ---------------------------------------------------------------------------
__global__ __launch_bounds__(512, 4)
void pq_kernel(const float* __restrict__ features,
               const double* __restrict__ wsd,
               double* __restrict__ P,
               double* __restrict__ Q,
               float* __restrict__ P32,
               float* __restrict__ Q32) {
    __shared__ float fts[64 * 132];
    const int t  = threadIdx.x;
    const int n0 = blockIdx.x * 64;
    const int sel = blockIdx.y;

    {
        const int n = t & 63, q = t >> 6;
        const int gn = n0 + n;
        #pragma unroll
        for (int i = 0; i < 4; ++i) {
            const int k = q * 16 + i * 4;
            float4 f = make_float4(0.f, 0.f, 0.f, 0.f);
            if (gn < N_NODES) f = *(const float4*)(features + (size_t)gn * HID + k);
            *(float4*)(&fts[n * 132 + k]) = f;
        }
    }
    __syncthreads();

    const int l  = t & 63;
    const int wv = __builtin_amdgcn_readfirstlane(t >> 6);
    const int j0 = wv * 16;
    const double* wb = wsd + W1D_OFF + (size_t)(sel * 128) * HID + j0;

    double acc[16];
    #pragma unroll
    for (int c = 0; c < 16; ++c) acc[c] = 0.0;

    const float* frow = &fts[l * 132];
    for (int k = 0; k < 128; k += 4) {
        float4 f = *(const float4*)(frow + k);
        #pragma unroll
        for (int kk = 0; kk < 4; ++kk) {
            const double fv = (double)((&f.x)[kk]);
            const double* wr = wb + (size_t)(k + kk) * HID;   // uniform -> s_load
            #pragma unroll
            for (int c = 0; c < 16; ++c)
                acc[c] = fma(fv, wr[c], acc[c]);
        }
    }

    const int gn = n0 + l;
    if (gn < N_NODES) {
        double* dst = (sel ? Q : P) + (size_t)gn * HID + j0;
        #pragma unroll
        for (int c = 0; c < 16; c += 2)
            *(double2*)(dst + c) = make_double2(acc[c], acc[c + 1]);
        float* dstf = (sel ? Q32 : P32) + (size_t)gn * HID + j0;
        #pragma unroll
        for (int c = 0; c < 16; c += 4)
            *(float4*)(dstf + c) = make_float4((float)acc[c], (float)acc[c + 1],
                                               (float)acc[c + 2], (float)acc[c + 3]);
    }
}

// ---------------------------------------------------------------------------
// Kernel 2 (pass A): layer-1 fp32 -> h1 split to bf16 hi/lo (swizzled LDS)
// -> layer-2 via bf16x3 MFMA (32x32x16, hi*hi + lo*hi + hi*lo, fp32 acc)
// -> layer-3 fp32 in-register -> exact-order z (fp64 sum of 4 fp32 partials).
// Persistent blocks: W2-hi fragments live in VGPRs across groups.
// Wave w: j-tile = (w&3)*32, edge-tile = (w>>2)*32.
// ---------------------------------------------------------------------------
__global__ __launch_bounds__(512, 4)
void edgeA_kernel(const int*   __restrict__ indices,
                  const float* __restrict__ values,
                  const float* __restrict__ P32,
                  const float* __restrict__ Q32,
                  const float* __restrict__ w1,
                  const float* __restrict__ b1,
                  const short* __restrict__ w2thi,
                  const short* __restrict__ w2tlo,
                  const float* __restrict__ b2,
                  const float* __restrict__ w3,
                  const float* __restrict__ b3,
                  double* __restrict__ zbuf) {
    __shared__ short h1hi[64 * 128];     // bf16 bits, XOR-swizzled rows
    __shared__ short h1lo[64 * 128];
    __shared__ float zpartS[4][64];      // per-j-tile layer-3 partials

    const int t  = threadIdx.x;
    const int l  = t & 63;
    const int wv = __builtin_amdgcn_readfirstlane(t >> 6);
    const int jt = wv & 3, et = wv >> 2;
    const int jj = jt * 32 + (l & 31);           // this lane's output column j
    const int khalf = (l >> 5) * 8;              // k sub-block for A/B frags

    // B fragments: lane supplies W2[k][jj] for k = s*16 + khalf + 0..7.
    // hi preloaded to VGPRs (reused across groups); lo read per group (L1/L2).
    short8 bhi[8];
    #pragma unroll
    for (int s = 0; s < 8; ++s)
        bhi[s] = *(const short8*)(w2thi + jj * 128 + s * 16 + khalf);
    const short* w2lo_l = w2tlo + jj * 128 + khalf;
    const float b2j = b2[jj];
    const float w3j = w3[jj];
    const float b3v = b3[0];

    const int e = l, q = t >> 6;                 // staging roles

    for (int grp = blockIdx.x; grp < NEDGE / 64; grp += GRID_A) {
        const int g0 = grp * 64;

        // ---- stage h1: fp32 layer-1, split to bf16 hi/lo, swizzled LDS ----
        {
            const int ge  = g0 + e;
            const int row = indices[ge];
            const int col = indices[NEDGE + ge];
            const float v = values[ge];
            const float* prow = P32 + (size_t)row * HID + q * 16;
            const float* qrow = Q32 + (size_t)col * HID + q * 16;
            const float* w1c  = w1 + (size_t)256 * HID + q * 16;  // uniform -> s_load
            const float* b1f  = b1 + q * 16;
            float h[16];
            #pragma unroll
            for (int i = 0; i < 16; i += 4) {
                float4 p  = *(const float4*)(prow + i);
                float4 qq = *(const float4*)(qrow + i);
                h[i]     = fmaxf(fmaf(v, w1c[i],     p.x + qq.x) + b1f[i],     0.f);
                h[i + 1] = fmaxf(fmaf(v, w1c[i + 1], p.y + qq.y) + b1f[i + 1], 0.f);
                h[i + 2] = fmaxf(fmaf(v, w1c[i + 2], p.z + qq.z) + b1f[i + 2], 0.f);
                h[i + 3] = fmaxf(fmaf(v, w1c[i + 3], p.w + qq.w) + b1f[i + 3], 0.f);
            }
            union { short s[8]; short8 v8; } H0, H1, L0, L1;
            #pragma unroll
            for (int i = 0; i < 8; ++i) {
                const unsigned short hiA = f2bf(h[i]);
                H0.s[i] = (short)hiA;
                L0.s[i] = (short)f2bf(h[i] - bf2f(hiA));
                const unsigned short hiB = f2bf(h[i + 8]);
                H1.s[i] = (short)hiB;
                L1.s[i] = (short)f2bf(h[i + 8] - bf2f(hiB));
            }
            // row = 256 B; XOR-swizzle 16B granules: byte ^= (e&7)<<4 (G4 fix)
            const int a0 = (e * 256 + q * 32) ^ ((e & 7) << 4);
            *(short8*)((char*)h1hi + a0)        = H0.v8;
            *(short8*)((char*)h1hi + (a0 ^ 16)) = H1.v8;
            *(short8*)((char*)h1lo + a0)        = L0.v8;
            *(short8*)((char*)h1lo + (a0 ^ 16)) = L1.v8;
        }
        __syncthreads();

        // ---- layer-2: bf16x3 MFMA, one 32x32 tile per wave, K = 8x16 ----
        f32x16 acc;
        #pragma unroll
        for (int r = 0; r < 16; ++r) acc[r] = 0.f;
        const int eA    = et * 32 + (l & 31);    // A row = edge
        const int abase = eA * 256;
        const int aswz  = (eA & 7) << 4;
        const int ah    = (l >> 5) * 16;
        #pragma unroll
        for (int s = 0; s < 8; ++s) {
            const int ao = (abase + s * 32 + ah) ^ aswz;
            const short8 ahi = *(const short8*)((const char*)h1hi + ao);
            const short8 alo = *(const short8*)((const char*)h1lo + ao);
            const short8 bl  = *(const short8*)(w2lo_l + s * 16);
            acc = __builtin_amdgcn_mfma_f32_32x32x16_bf16(ahi, bhi[s], acc, 0, 0, 0);
            acc = __builtin_amdgcn_mfma_f32_32x32x16_bf16(alo, bhi[s], acc, 0, 0, 0);
            acc = __builtin_amdgcn_mfma_f32_32x32x16_bf16(ahi, bl,     acc, 0, 0, 0);
        }

        // ---- layer-3: per-edge dot with w3 over this wave's 32 j's ----
        // C/D map: col = l&31 (=j), row(edge) = (r&3) + 8*(r>>2) + 4*(l>>5)
        #pragma unroll
        for (int r = 0; r < 16; ++r) {
            float hv = fmaxf(acc[r] + b2j, 0.f) * w3j;
            #pragma unroll
            for (int d = 1; d < 32; d <<= 1) hv += __shfl_xor(hv, d);  // 32-lane sum
            acc[r] = hv;
        }
        if ((l & 31) == 0) {
            #pragma unroll
            for (int r = 0; r < 16; ++r)
                zpartS[jt][et * 32 + (r & 3) + 8 * (r >> 2) + 4 * (l >> 5)] = acc[r];
        }
        __syncthreads();

        // ---- exact z: ordered fp64 sum of the 4 fp32 j-tile partials ----
        if (t < 64) {
            double z = (double)b3v;
            z += (double)zpartS[0][t];
            z += (double)zpartS[1][t];
            z += (double)zpartS[2][t];
            z += (double)zpartS[3][t];
            zbuf[g0 + t] = z;
        }
        // next staging writes h1 only (ordered vs our MFMA reads by the 2nd
        // barrier); zpartS next written after the next 1st barrier.
    }
}

// ---------------------------------------------------------------------------
// Kernel 2b: fp64 epilogue over all edges (1 thread/edge, 16-lane groups).
// Writes out; flags near-boundary nodes for fp64 repair. (unchanged)
// ---------------------------------------------------------------------------
__global__ __launch_bounds__(256, 8)
void epi_kernel(const double* __restrict__ zbuf,
                const float*  __restrict__ tempr,
                int*          __restrict__ fcnt,
                int*          __restrict__ flist,
                float*        __restrict__ out) {
    const int t  = threadIdx.x;
    const int ge = blockIdx.x * 256 + t;
    const int lane = t & 63;
    const int base = lane & 48;

    const double z = zbuf[ge];
    const double T = (double)tempr[0];

    double m = z;
    #pragma unroll
    for (int d = 1; d < 16; d <<= 1) m = fmax(m, __shfl_xor(m, d));
    const double e1 = exp(z - m);
    double s = 0.0;
    #pragma unroll
    for (int k = 0; k < 16; ++k) s += __shfl(e1, base + k);
    const double pi = e1 / s;

    const double x  = log(pi + 1e-8) / T;
    double hard = 1.0 / (1.0 + exp(-x));
    hard = fmin(fmax(hard, 0.0), 1.0);

    double m2 = hard;
    #pragma unroll
    for (int d = 1; d < 16; d <<= 1) m2 = fmax(m2, __shfl_xor(m2, d));
    const double e2 = exp(hard - m2);
    double s2 = 0.0;
    #pragma unroll
    for (int k = 0; k < 16; ++k) s2 += __shfl(e2, base + k);
    const double y = e2 / s2;

    int cgt = 0, ceq = 0;
    #pragma unroll
    for (int j = 0; j < 16; ++j) {
        const double yj = __shfl(y, base + j);
        cgt += (yj > y);
        ceq += (yj == y);
    }
    double cand = (cgt <= 7 && cgt + ceq >= 8) ? y : -1.0e300;
    double thre = cand;
    #pragma unroll
    for (int d = 1; d < 16; d <<= 1) thre = fmax(thre, __shfl_xor(thre, d));

    const double g = (y - thre) + 1e-7;
    out[ge] = (g > 0.0) ? (float)y : 0.0f;

    const bool near = (y != thre) && (fabs(g) < TAU);
    const unsigned long long ball = __ballot(near);
    if ((lane & 15) == 0) {
        if ((ball >> base) & 0xFFFFull) {
            const int nid = ge >> 4;
            const int idx = atomicAdd(fcnt, 1);
            flist[idx] = nid;
        }
    }
}

// ---------------------------------------------------------------------------
// Kernel 3 (pass B): exact fp64 pipeline for flagged nodes only. (unchanged)
// ---------------------------------------------------------------------------
__global__ __launch_bounds__(512, 4)
void edgeB_kernel(const int*   __restrict__ indices,
                  const float* __restrict__ values,
                  const float* __restrict__ tempr,
                  const double* __restrict__ wsd,
                  const double* __restrict__ P,
                  const double* __restrict__ Q,
                  const int*   __restrict__ fcnt,
                  const int*   __restrict__ flist,
                  float* __restrict__ out) {
    __shared__ double h1s[64 * LDSP];
    __shared__ double zpart[8][64];
    __shared__ int nids[4];
    const int t = threadIdx.x;
    const int cnt = *fcnt;

    for (int g0 = blockIdx.x * 4; g0 < cnt; g0 += gridDim.x * 4) {
        if (t < 4) nids[t] = (g0 + t < cnt) ? flist[g0 + t] : -1;
        __syncthreads();

        {
            const int e = t & 63, q = t >> 6;
            const int node = nids[e >> 4];
            double* hdst = &h1s[e * LDSP + q * 16];
            if (node >= 0) {
                const int ge = node * 16 + (e & 15);
                const int row = indices[ge];
                const int col = indices[NEDGE + ge];
                const double v = (double)values[ge];
                const double* prow = P + (size_t)row * HID + q * 16;
                const double* qrow = Q + (size_t)col * HID + q * 16;
                const double* w1c  = wsd + W1D_OFF + (size_t)256 * HID + q * 16;
                const double* b1d  = wsd + B1D_OFF + q * 16;
                #pragma unroll
                for (int i = 0; i < 16; i += 2) {
                    double2 p  = *(const double2*)(prow + i);
                    double2 qq = *(const double2*)(qrow + i);
                    hdst[i]     = fmax(fma(v, w1c[i],     p.x + qq.x) + b1d[i],     0.0);
                    hdst[i + 1] = fmax(fma(v, w1c[i + 1], p.y + qq.y) + b1d[i + 1], 0.0);
                }
            } else {
                #pragma unroll
                for (int i = 0; i < 16; ++i) hdst[i] = 0.0;
            }
        }
        __syncthreads();

        const int l  = t & 63;
        const int wv = __builtin_amdgcn_readfirstlane(t >> 6);
        const int j0 = wv * 16;
        const double* w2b = wsd + W2D_OFF + j0;

        double acc[16];
        #pragma unroll
        for (int c = 0; c < 16; ++c) acc[c] = 0.0;

        const double* hrow = &h1s[l * LDSP];
        for (int k = 0; k < 128; k += 2) {
            const double h0  = hrow[k];
            const double h1v = hrow[k + 1];
            const double* wr0 = w2b + (size_t)k * HID;
            const double* wr1 = wr0 + HID;
            #pragma unroll
            for (int c = 0; c < 16; ++c) acc[c] = fma(h0,  wr0[c], acc[c]);
            #pragma unroll
            for (int c = 0; c < 16; ++c) acc[c] = fma(h1v, wr1[c], acc[c]);
        }

        {
            const double* b2d = wsd + B2D_OFF + j0;
            const double* w3d = wsd + W3D_OFF + j0;
            double part = 0.0;
            #pragma unroll
            for (int c = 0; c < 16; ++c) {
                const double h2 = fmax(acc[c] + b2d[c], 0.0);
                part = fma(h2, w3d[c], part);
            }
            zpart[wv][l] = part;
        }
        __syncthreads();

        if (t < 64) {
            double z = wsd[B3D_OFF];
            #pragma unroll
            for (int w = 0; w < 8; ++w) z += zpart[w][t];

            const double T = (double)tempr[0];
            const int base = t & 48;

            double m = z;
            #pragma unroll
            for (int d = 1; d < 16; d <<= 1) m = fmax(m, __shfl_xor(m, d));
            const double e1 = exp(z - m);
            double s = 0.0;
            #pragma unroll
            for (int k = 0; k < 16; ++k) s += __shfl(e1, base + k);
            const double pi = e1 / s;

            const double x  = log(pi + 1e-8) / T;
            double hard = 1.0 / (1.0 + exp(-x));
            hard = fmin(fmax(hard, 0.0), 1.0);

            double m2 = hard;
            #pragma unroll
            for (int d = 1; d < 16; d <<= 1) m2 = fmax(m2, __shfl_xor(m2, d));
            const double e2 = exp(hard - m2);
            double s2 = 0.0;
            #pragma unroll
            for (int k = 0; k < 16; ++k) s2 += __shfl(e2, base + k);
            const double y = e2 / s2;

            int cgt = 0, ceq = 0;
            #pragma unroll
            for (int j = 0; j < 16; ++j) {
                const double yj = __shfl(y, base + j);
                cgt += (yj > y);
                ceq += (yj == y);
            }
            double cand = (cgt <= 7 && cgt + ceq >= 8) ? y : -1.0e300;
            double thre = cand;
            #pragma unroll
            for (int d = 1; d < 16; d <<= 1) thre = fmax(thre, __shfl_xor(thre, d));

            const double g = (y - thre) + 1e-7;
            const int node = nids[t >> 4];
            if (node >= 0)
                out[node * 16 + (t & 15)] = (g > 0.0) ? (float)y : 0.0f;
        }
        __syncthreads();
    }
}

// ---------------------------------------------------------------------------
extern "C" void kernel_launch(void* const* d_in, const int* in_sizes, int n_in,
                              void* d_out, int out_size, void* d_ws, size_t ws_size,
                              hipStream_t stream) {
    const float* features = (const float*)d_in[0];
    const int*   indices  = (const int*)  d_in[1];
    const float* values   = (const float*)d_in[2];
    const float* tempr    = (const float*)d_in[3];
    const float* w1       = (const float*)d_in[4];
    const float* b1       = (const float*)d_in[5];
    const float* w2       = (const float*)d_in[6];
    const float* b2       = (const float*)d_in[7];
    const float* w3       = (const float*)d_in[8];
    const float* b3       = (const float*)d_in[9];
    float* out = (float*)d_out;

    double* wsd = (double*)d_ws;
    double* P64 = wsd + PQ64_OFF;
    double* Q64 = P64 + (size_t)N_NODES * HID;
    float*  P32 = (float*)(wsd + P32_OFF_D);
    float*  Q32 = P32 + (size_t)N_NODES * HID;
    int*    fcnt  = (int*)(wsd + FLAG_OFF_D);
    int*    flist = fcnt + 1;
    double* zbuf  = wsd + Z_OFF_D;
    const short* w2thi = (const short*)(wsd + W2THI_OFF_D);
    const short* w2tlo = (const short*)(wsd + W2TLO_OFF_D);

    conv_kernel<<<(NWCONV + 255) / 256, 256, 0, stream>>>(w1, b1, w2, b2, w3, b3, wsd);

    dim3 g1((N_NODES + 63) / 64, 2);
    pq_kernel<<<g1, 512, 0, stream>>>(features, wsd, P64, Q64, P32, Q32);

    edgeA_kernel<<<GRID_A, 512, 0, stream>>>(indices, values, P32, Q32,
                                             w1, b1, w2thi, w2tlo, b2, w3, b3, zbuf);

    epi_kernel<<<NEDGE / 256, 256, 0, stream>>>(zbuf, tempr, fcnt, flist, out);

    edgeB_kernel<<<512, 512, 0, stream>>>(indices, values, tempr, wsd, P64, Q64,
                                          fcnt, flist, out);
}

// Round 7
// 574.256 us; speedup vs baseline: 1.0435x; 1.0435x over previous
//
#include <hip/hip_runtime.h>

#define N_NODES 50000
#define NEDGE   800000
#define HID     128
#define LDSP    129          // doubles per LDS row (fp64 repair kernel)
#define TAU     2.5e-7       // flag margin: must exceed 1e-7 ref-slack + 2*dy

// ---- workspace layout (units: doubles) ----
#define W1D_OFF 0            // 257*128 = 32896, row-major [k][j]
#define B1D_OFF 32896        // 128
#define W2D_OFF 33024        // 128*128 = 16384
#define B2D_OFF 49408        // 128
#define W3D_OFF 49536        // 128
#define B3D_OFF 49664        // 1
#define NWCONV  49665
#define PQ64_OFF 49672                                        // P64,Q64: each N*128 doubles
#define P32_OFF_D  (PQ64_OFF + 2ull * N_NODES * HID)          // P32,Q32 floats overlay
#define FLAG_OFF_D (P32_OFF_D + 1ull * N_NODES * HID)         // int cnt + int list[N]
#define Z_OFF_D    (FLAG_OFF_D + 25008)                       // z[NEDGE] doubles
#define W2THI_OFF_D (Z_OFF_D + NEDGE)                         // W2^T bf16 hi [j][k] 16384 shorts
#define W2TLO_OFF_D (W2THI_OFF_D + 4096)                      // W2^T bf16 lo
// total ~161 MB < 256 MiB workspace

typedef __attribute__((ext_vector_type(8)))  short short8;
typedef __attribute__((ext_vector_type(16))) float f32x16;

__device__ __forceinline__ unsigned short f2bf(float f) {
    const unsigned u = __float_as_uint(f);
    const unsigned r = u + 0x7FFFu + ((u >> 16) & 1u);   // RN-even; inputs finite
    return (unsigned short)(r >> 16);
}
__device__ __forceinline__ float bf2f(unsigned short h) {
    return __uint_as_float((unsigned)h << 16);
}

// ---------------------------------------------------------------------------
// Kernel 0: convert weights to fp64 (for exact repair path) + W2^T bf16 hi/lo
// (for the MFMA fast pass); zero the flagged-node counter.
// ---------------------------------------------------------------------------
__global__ void conv_kernel(const float* __restrict__ w1, const float* __restrict__ b1,
                            const float* __restrict__ w2, const float* __restrict__ b2,
                            const float* __restrict__ w3, const float* __restrict__ b3,
                            double* __restrict__ wsd) {
    const int i = blockIdx.x * 256 + threadIdx.x;
    if (i == 0) *(int*)(wsd + FLAG_OFF_D) = 0;
    if (i < 16384) {                       // W2^T split: [j][k] from w2[k][j]
        const int k = i >> 7, j = i & 127;
        const float v = w2[i];
        const unsigned short hi = f2bf(v);
        const unsigned short lo = f2bf(v - bf2f(hi));
        short* w2thi = (short*)(wsd + W2THI_OFF_D);
        short* w2tlo = (short*)(wsd + W2TLO_OFF_D);
        w2thi[j * 128 + k] = (short)hi;
        w2tlo[j * 128 + k] = (short)lo;
    }
    if (i >= NWCONV) return;
    float v;
    if      (i < B1D_OFF) v = w1[i];
    else if (i < W2D_OFF) v = b1[i - B1D_OFF];
    else if (i < B2D_OFF) v = w2[i - W2D_OFF];
    else if (i < W3D_OFF) v = b2[i - B2D_OFF];
    else if (i < B3D_OFF) v = w3[i - W3D_OFF];
    else                  v = b3[0];
    wsd[i] = (double)v;
}

// ---------------------------------------------------------------------------
// Kernel 1: P[n][j] = sum_k f[n][k] w1[k][j] (sel=0), Q with rows 128..255.
// fp64 accumulate; also writes fp32 copies for the fast pass. (unchanged)
// ---------------------------------------------------------------------------
__global__ __launch_bounds__(512, 4)
void pq_kernel(const float* __restrict__ features,
               const double* __restrict__ wsd,
               double* __restrict__ P,
               double* __restrict__ Q,
               float* __restrict__ P32,
               float* __restrict__ Q32) {
    __shared__ float fts[64 * 132];
    const int t  = threadIdx.x;
    const int n0 = blockIdx.x * 64;
    const int sel = blockIdx.y;

    {
        const int n = t & 63, q = t >> 6;
        const int gn = n0 + n;
        #pragma unroll
        for (int i = 0; i < 4; ++i) {
            const int k = q * 16 + i * 4;
            float4 f = make_float4(0.f, 0.f, 0.f, 0.f);
            if (gn < N_NODES) f = *(const float4*)(features + (size_t)gn * HID + k);
            *(float4*)(&fts[n * 132 + k]) = f;
        }
    }
    __syncthreads();

    const int l  = t & 63;
    const int wv = __builtin_amdgcn_readfirstlane(t >> 6);
    const int j0 = wv * 16;
    const double* wb = wsd + W1D_OFF + (size_t)(sel * 128) * HID + j0;

    double acc[16];
    #pragma unroll
    for (int c = 0; c < 16; ++c) acc[c] = 0.0;

    const float* frow = &fts[l * 132];
    for (int k = 0; k < 128; k += 4) {
        float4 f = *(const float4*)(frow + k);
        #pragma unroll
        for (int kk = 0; kk < 4; ++kk) {
            const double fv = (double)((&f.x)[kk]);
            const double* wr = wb + (size_t)(k + kk) * HID;   // uniform -> s_load
            #pragma unroll
            for (int c = 0; c < 16; ++c)
                acc[c] = fma(fv, wr[c], acc[c]);
        }
    }

    const int gn = n0 + l;
    if (gn < N_NODES) {
        double* dst = (sel ? Q : P) + (size_t)gn * HID + j0;
        #pragma unroll
        for (int c = 0; c < 16; c += 2)
            *(double2*)(dst + c) = make_double2(acc[c], acc[c + 1]);
        float* dstf = (sel ? Q32 : P32) + (size_t)gn * HID + j0;
        #pragma unroll
        for (int c = 0; c < 16; c += 4)
            *(float4*)(dstf + c) = make_float4((float)acc[c], (float)acc[c + 1],
                                               (float)acc[c + 2], (float)acc[c + 3]);
    }
}

// ---------------------------------------------------------------------------
// Kernel 2 (pass A): layer-1 fp32 -> h1 split to bf16 hi/lo (swizzled LDS)
// -> layer-2 via bf16x3 MFMA (32x32x16, hi*hi + lo*hi + hi*lo, fp32 acc)
// -> layer-3 fp32 in-register -> exact-order z (fp64 sum of 4 fp32 partials).
// One block per 64-edge group (in-order dispatch -> P-row L2 locality).
// B hi/lo fragments loaded from global INSIDE the s-loop (L1/L2-hot 64 KB
// table) -- no long-lived VGPR array, no spill (round-5 lesson: the bhi[8]
// preload spilled to scratch: WRITE 166 MB, FETCH +467 MB).
// ---------------------------------------------------------------------------
__global__ __launch_bounds__(512, 4)
void edgeA_kernel(const int*   __restrict__ indices,
                  const float* __restrict__ values,
                  const float* __restrict__ P32,
                  const float* __restrict__ Q32,
                  const float* __restrict__ w1,
                  const float* __restrict__ b1,
                  const short* __restrict__ w2thi,
                  const short* __restrict__ w2tlo,
                  const float* __restrict__ b2,
                  const float* __restrict__ w3,
                  const float* __restrict__ b3,
                  double* __restrict__ zbuf) {
    __shared__ short h1hi[64 * 128];     // bf16 bits, XOR-swizzled rows
    __shared__ short h1lo[64 * 128];
    __shared__ float zpartS[4][64];      // per-j-tile layer-3 partials

    const int t  = threadIdx.x;
    const int e0 = blockIdx.x * 64;

    // ---- stage h1: fp32 layer-1, split to bf16 hi/lo, swizzled LDS ----
    {
        const int e = t & 63, q = t >> 6;
        const int ge  = e0 + e;
        const int row = indices[ge];
        const int col = indices[NEDGE + ge];
        const float v = values[ge];
        const float* prow = P32 + (size_t)row * HID + q * 16;
        const float* qrow = Q32 + (size_t)col * HID + q * 16;
        const float* w1c  = w1 + (size_t)256 * HID + q * 16;  // uniform -> s_load
        const float* b1f  = b1 + q * 16;
        float h[16];
        #pragma unroll
        for (int i = 0; i < 16; i += 4) {
            float4 p  = *(const float4*)(prow + i);
            float4 qq = *(const float4*)(qrow + i);
            h[i]     = fmaxf(fmaf(v, w1c[i],     p.x + qq.x) + b1f[i],     0.f);
            h[i + 1] = fmaxf(fmaf(v, w1c[i + 1], p.y + qq.y) + b1f[i + 1], 0.f);
            h[i + 2] = fmaxf(fmaf(v, w1c[i + 2], p.z + qq.z) + b1f[i + 2], 0.f);
            h[i + 3] = fmaxf(fmaf(v, w1c[i + 3], p.w + qq.w) + b1f[i + 3], 0.f);
        }
        union { short s[8]; short8 v8; } H0, H1, L0, L1;
        #pragma unroll
        for (int i = 0; i < 8; ++i) {
            const unsigned short hiA = f2bf(h[i]);
            H0.s[i] = (short)hiA;
            L0.s[i] = (short)f2bf(h[i] - bf2f(hiA));
            const unsigned short hiB = f2bf(h[i + 8]);
            H1.s[i] = (short)hiB;
            L1.s[i] = (short)f2bf(h[i + 8] - bf2f(hiB));
        }
        // row = 256 B; XOR-swizzle 16B granules: byte ^= (e&7)<<4 (G4 fix)
        const int a0 = (e * 256 + q * 32) ^ ((e & 7) << 4);
        *(short8*)((char*)h1hi + a0)        = H0.v8;
        *(short8*)((char*)h1hi + (a0 ^ 16)) = H1.v8;
        *(short8*)((char*)h1lo + a0)        = L0.v8;
        *(short8*)((char*)h1lo + (a0 ^ 16)) = L1.v8;
    }
    __syncthreads();

    // ---- layer-2: bf16x3 MFMA, one 32x32 tile per wave, K = 8x16 ----
    const int l  = t & 63;
    const int wv = __builtin_amdgcn_readfirstlane(t >> 6);
    const int jt = wv & 3, et = wv >> 2;
    const int jj = jt * 32 + (l & 31);           // this lane's output column j
    const int khalf = (l >> 5) * 8;              // k sub-block for A/B frags
    const short* w2hi_l = w2thi + jj * 128 + khalf;
    const short* w2lo_l = w2tlo + jj * 128 + khalf;

    f32x16 acc;
    #pragma unroll
    for (int r = 0; r < 16; ++r) acc[r] = 0.f;
    const int eA    = et * 32 + (l & 31);        // A row = edge
    const int abase = eA * 256;
    const int aswz  = (eA & 7) << 4;
    const int ah    = (l >> 5) * 16;
    #pragma unroll 2
    for (int s = 0; s < 8; ++s) {
        const int ao = (abase + s * 32 + ah) ^ aswz;
        const short8 ahi = *(const short8*)((const char*)h1hi + ao);
        const short8 alo = *(const short8*)((const char*)h1lo + ao);
        const short8 bh  = *(const short8*)(w2hi_l + s * 16);
        const short8 bl  = *(const short8*)(w2lo_l + s * 16);
        acc = __builtin_amdgcn_mfma_f32_32x32x16_bf16(ahi, bh, acc, 0, 0, 0);
        acc = __builtin_amdgcn_mfma_f32_32x32x16_bf16(alo, bh, acc, 0, 0, 0);
        acc = __builtin_amdgcn_mfma_f32_32x32x16_bf16(ahi, bl, acc, 0, 0, 0);
    }

    // ---- layer-3: per-edge dot with w3 over this wave's 32 j's ----
    // C/D map: col = l&31 (=j), row(edge) = (r&3) + 8*(r>>2) + 4*(l>>5)
    const float b2j = b2[jj];
    const float w3j = w3[jj];
    #pragma unroll
    for (int r = 0; r < 16; ++r) {
        float hv = fmaxf(acc[r] + b2j, 0.f) * w3j;
        #pragma unroll
        for (int d = 1; d < 32; d <<= 1) hv += __shfl_xor(hv, d);  // 32-lane sum
        acc[r] = hv;
    }
    if ((l & 31) == 0) {
        #pragma unroll
        for (int r = 0; r < 16; ++r)
            zpartS[jt][et * 32 + (r & 3) + 8 * (r >> 2) + 4 * (l >> 5)] = acc[r];
    }
    __syncthreads();

    // ---- exact z: ordered fp64 sum of the 4 fp32 j-tile partials ----
    if (t < 64) {
        double z = (double)b3[0];
        z += (double)zpartS[0][t];
        z += (double)zpartS[1][t];
        z += (double)zpartS[2][t];
        z += (double)zpartS[3][t];
        zbuf[e0 + t] = z;
    }
}

// ---------------------------------------------------------------------------
// Kernel 2b: fp64 epilogue over all edges (1 thread/edge, 16-lane groups).
// Writes out; flags near-boundary nodes for fp64 repair. (unchanged)
// ---------------------------------------------------------------------------
__global__ __launch_bounds__(256, 8)
void epi_kernel(const double* __restrict__ zbuf,
                const float*  __restrict__ tempr,
                int*          __restrict__ fcnt,
                int*          __restrict__ flist,
                float*        __restrict__ out) {
    const int t  = threadIdx.x;
    const int ge = blockIdx.x * 256 + t;
    const int lane = t & 63;
    const int base = lane & 48;

    const double z = zbuf[ge];
    const double T = (double)tempr[0];

    double m = z;
    #pragma unroll
    for (int d = 1; d < 16; d <<= 1) m = fmax(m, __shfl_xor(m, d));
    const double e1 = exp(z - m);
    double s = 0.0;
    #pragma unroll
    for (int k = 0; k < 16; ++k) s += __shfl(e1, base + k);
    const double pi = e1 / s;

    const double x  = log(pi + 1e-8) / T;
    double hard = 1.0 / (1.0 + exp(-x));
    hard = fmin(fmax(hard, 0.0), 1.0);

    double m2 = hard;
    #pragma unroll
    for (int d = 1; d < 16; d <<= 1) m2 = fmax(m2, __shfl_xor(m2, d));
    const double e2 = exp(hard - m2);
    double s2 = 0.0;
    #pragma unroll
    for (int k = 0; k < 16; ++k) s2 += __shfl(e2, base + k);
    const double y = e2 / s2;

    int cgt = 0, ceq = 0;
    #pragma unroll
    for (int j = 0; j < 16; ++j) {
        const double yj = __shfl(y, base + j);
        cgt += (yj > y);
        ceq += (yj == y);
    }
    double cand = (cgt <= 7 && cgt + ceq >= 8) ? y : -1.0e300;
    double thre = cand;
    #pragma unroll
    for (int d = 1; d < 16; d <<= 1) thre = fmax(thre, __shfl_xor(thre, d));

    const double g = (y - thre) + 1e-7;
    out[ge] = (g > 0.0) ? (float)y : 0.0f;

    const bool near = (y != thre) && (fabs(g) < TAU);
    const unsigned long long ball = __ballot(near);
    if ((lane & 15) == 0) {
        if ((ball >> base) & 0xFFFFull) {
            const int nid = ge >> 4;
            const int idx = atomicAdd(fcnt, 1);
            flist[idx] = nid;
        }
    }
}

// ---------------------------------------------------------------------------
// Kernel 3 (pass B): exact fp64 pipeline for flagged nodes only. (unchanged)
// ---------------------------------------------------------------------------
__global__ __launch_bounds__(512, 4)
void edgeB_kernel(const int*   __restrict__ indices,
                  const float* __restrict__ values,
                  const float* __restrict__ tempr,
                  const double* __restrict__ wsd,
                  const double* __restrict__ P,
                  const double* __restrict__ Q,
                  const int*   __restrict__ fcnt,
                  const int*   __restrict__ flist,
                  float* __restrict__ out) {
    __shared__ double h1s[64 * LDSP];
    __shared__ double zpart[8][64];
    __shared__ int nids[4];
    const int t = threadIdx.x;
    const int cnt = *fcnt;

    for (int g0 = blockIdx.x * 4; g0 < cnt; g0 += gridDim.x * 4) {
        if (t < 4) nids[t] = (g0 + t < cnt) ? flist[g0 + t] : -1;
        __syncthreads();

        {
            const int e = t & 63, q = t >> 6;
            const int node = nids[e >> 4];
            double* hdst = &h1s[e * LDSP + q * 16];
            if (node >= 0) {
                const int ge = node * 16 + (e & 15);
                const int row = indices[ge];
                const int col = indices[NEDGE + ge];
                const double v = (double)values[ge];
                const double* prow = P + (size_t)row * HID + q * 16;
                const double* qrow = Q + (size_t)col * HID + q * 16;
                const double* w1c  = wsd + W1D_OFF + (size_t)256 * HID + q * 16;
                const double* b1d  = wsd + B1D_OFF + q * 16;
                #pragma unroll
                for (int i = 0; i < 16; i += 2) {
                    double2 p  = *(const double2*)(prow + i);
                    double2 qq = *(const double2*)(qrow + i);
                    hdst[i]     = fmax(fma(v, w1c[i],     p.x + qq.x) + b1d[i],     0.0);
                    hdst[i + 1] = fmax(fma(v, w1c[i + 1], p.y + qq.y) + b1d[i + 1], 0.0);
                }
            } else {
                #pragma unroll
                for (int i = 0; i < 16; ++i) hdst[i] = 0.0;
            }
        }
        __syncthreads();

        const int l  = t & 63;
        const int wv = __builtin_amdgcn_readfirstlane(t >> 6);
        const int j0 = wv * 16;
        const double* w2b = wsd + W2D_OFF + j0;

        double acc[16];
        #pragma unroll
        for (int c = 0; c < 16; ++c) acc[c] = 0.0;

        const double* hrow = &h1s[l * LDSP];
        for (int k = 0; k < 128; k += 2) {
            const double h0  = hrow[k];
            const double h1v = hrow[k + 1];
            const double* wr0 = w2b + (size_t)k * HID;
            const double* wr1 = wr0 + HID;
            #pragma unroll
            for (int c = 0; c < 16; ++c) acc[c] = fma(h0,  wr0[c], acc[c]);
            #pragma unroll
            for (int c = 0; c < 16; ++c) acc[c] = fma(h1v, wr1[c], acc[c]);
        }

        {
            const double* b2d = wsd + B2D_OFF + j0;
            const double* w3d = wsd + W3D_OFF + j0;
            double part = 0.0;
            #pragma unroll
            for (int c = 0; c < 16; ++c) {
                const double h2 = fmax(acc[c] + b2d[c], 0.0);
                part = fma(h2, w3d[c], part);
            }
            zpart[wv][l] = part;
        }
        __syncthreads();

        if (t < 64) {
            double z = wsd[B3D_OFF];
            #pragma unroll
            for (int w = 0; w < 8; ++w) z += zpart[w][t];

            const double T = (double)tempr[0];
            const int base = t & 48;

            double m = z;
            #pragma unroll
            for (int d = 1; d < 16; d <<= 1) m = fmax(m, __shfl_xor(m, d));
            const double e1 = exp(z - m);
            double s = 0.0;
            #pragma unroll
            for (int k = 0; k < 16; ++k) s += __shfl(e1, base + k);
            const double pi = e1 / s;

            const double x  = log(pi + 1e-8) / T;
            double hard = 1.0 / (1.0 + exp(-x));
            hard = fmin(fmax(hard, 0.0), 1.0);

            double m2 = hard;
            #pragma unroll
            for (int d = 1; d < 16; d <<= 1) m2 = fmax(m2, __shfl_xor(m2, d));
            const double e2 = exp(hard - m2);
            double s2 = 0.0;
            #pragma unroll
            for (int k = 0; k < 16; ++k) s2 += __shfl(e2, base + k);
            const double y = e2 / s2;

            int cgt = 0, ceq = 0;
            #pragma unroll
            for (int j = 0; j < 16; ++j) {
                const double yj = __shfl(y, base + j);
                cgt += (yj > y);
                ceq += (yj == y);
            }
            double cand = (cgt <= 7 && cgt + ceq >= 8) ? y : -1.0e300;
            double thre = cand;
            #pragma unroll
            for (int d = 1; d < 16; d <<= 1) thre = fmax(thre, __shfl_xor(thre, d));

            const double g = (y - thre) + 1e-7;
            const int node = nids[t >> 4];
            if (node >= 0)
                out[node * 16 + (t & 15)] = (g > 0.0) ? (float)y : 0.0f;
        }
        __syncthreads();
    }
}

// ---------------------------------------------------------------------------
extern "C" void kernel_launch(void* const* d_in, const int* in_sizes, int n_in,
                              void* d_out, int out_size, void* d_ws, size_t ws_size,
                              hipStream_t stream) {
    const float* features = (const float*)d_in[0];
    const int*   indices  = (const int*)  d_in[1];
    const float* values   = (const float*)d_in[2];
    const float* tempr    = (const float*)d_in[3];
    const float* w1       = (const float*)d_in[4];
    const float* b1       = (const float*)d_in[5];
    const float* w2       = (const float*)d_in[6];
    const float* b2       = (const float*)d_in[7];
    const float* w3       = (const float*)d_in[8];
    const float* b3       = (const float*)d_in[9];
    float* out = (float*)d_out;

    double* wsd = (double*)d_ws;
    double* P64 = wsd + PQ64_OFF;
    double* Q64 = P64 + (size_t)N_NODES * HID;
    float*  P32 = (float*)(wsd + P32_OFF_D);
    float*  Q32 = P32 + (size_t)N_NODES * HID;
    int*    fcnt  = (int*)(wsd + FLAG_OFF_D);
    int*    flist = fcnt + 1;
    double* zbuf  = wsd + Z_OFF_D;
    const short* w2thi = (const short*)(wsd + W2THI_OFF_D);
    const short* w2tlo = (const short*)(wsd + W2TLO_OFF_D);

    conv_kernel<<<(NWCONV + 255) / 256, 256, 0, stream>>>(w1, b1, w2, b2, w3, b3, wsd);

    dim3 g1((N_NODES + 63) / 64, 2);
    pq_kernel<<<g1, 512, 0, stream>>>(features, wsd, P64, Q64, P32, Q32);

    edgeA_kernel<<<NEDGE / 64, 512, 0, stream>>>(indices, values, P32, Q32,
                                                 w1, b1, w2thi, w2tlo, b2, w3, b3, zbuf);

    epi_kernel<<<NEDGE / 256, 256, 0, stream>>>(zbuf, tempr, fcnt, flist, out);

    edgeB_kernel<<<512, 512, 0, stream>>>(indices, values, tempr, wsd, P64, Q64,
                                          fcnt, flist, out);
}

// Round 8
// 450.713 us; speedup vs baseline: 1.3295x; 1.2741x over previous
//
#include <hip/hip_runtime.h>

#define N_NODES 50000
#define NEDGE   800000
#define HID     128
#define LDSP    129          // doubles per LDS row (fp64 repair kernel)
#define TAU     2.5e-7       // flag margin: must exceed 1e-7 ref-slack + 2*dy

// ---- workspace layout (units: doubles) ----
#define W1D_OFF 0            // 257*128 = 32896, row-major [k][j]
#define B1D_OFF 32896        // 128
#define W2D_OFF 33024        // 128*128 = 16384
#define B2D_OFF 49408        // 128
#define W3D_OFF 49536        // 128
#define B3D_OFF 49664        // 1
#define NWCONV  49665
#define PQ64_OFF 49672                                        // P64,Q64: each N*128 doubles
#define P32_OFF_D  (PQ64_OFF + 2ull * N_NODES * HID)          // P32,Q32 floats overlay
#define FLAG_OFF_D (P32_OFF_D + 1ull * N_NODES * HID)         // int cnt + int list[N]
#define Z_OFF_D    (FLAG_OFF_D + 25008)                       // z[NEDGE] doubles
#define W2FHI_OFF_D (Z_OFF_D + NEDGE)                         // W2 frag-order bf16 hi, 16384 shorts
#define W2FLO_OFF_D (W2FHI_OFF_D + 4096)                      // W2 frag-order bf16 lo
// total ~161 MB < 256 MiB workspace

typedef __attribute__((ext_vector_type(8)))  short short8;
typedef __attribute__((ext_vector_type(16))) float f32x16;

__device__ __forceinline__ unsigned short f2bf(float f) {
    const unsigned u = __float_as_uint(f);
    const unsigned r = u + 0x7FFFu + ((u >> 16) & 1u);   // RN-even; inputs finite
    return (unsigned short)(r >> 16);
}
__device__ __forceinline__ float bf2f(unsigned short h) {
    return __uint_as_float((unsigned)h << 16);
}

// ---------------------------------------------------------------------------
// Kernel 0: convert weights to fp64 (exact repair path) + W2 bf16 hi/lo in
// MFMA FRAGMENT ORDER (coalesced per-lane 16B: idx = ((s*4+jt)*64+l)*8+c
// holds w2[k][jj], k = s*16+(l>>5)*8+c, jj = jt*32+(l&31)).  Round-7 lesson:
// the [j][k] layout made every B-frag load a 64-cache-line scatter (L1
// thrash, ~512KB L2/block).  Also zero the flagged-node counter.
// ---------------------------------------------------------------------------
__global__ void conv_kernel(const float* __restrict__ w1, const float* __restrict__ b1,
                            const float* __restrict__ w2, const float* __restrict__ b2,
                            const float* __restrict__ w3, const float* __restrict__ b3,
                            double* __restrict__ wsd) {
    const int i = blockIdx.x * 256 + threadIdx.x;
    if (i == 0) *(int*)(wsd + FLAG_OFF_D) = 0;
    if (i < 16384) {
        const int c  = i & 7;
        const int l  = (i >> 3) & 63;
        const int jt = (i >> 9) & 3;
        const int s  = i >> 11;
        const int jj = jt * 32 + (l & 31);
        const int k  = s * 16 + (l >> 5) * 8 + c;
        const float v = w2[k * 128 + jj];
        const unsigned short hi = f2bf(v);
        const unsigned short lo = f2bf(v - bf2f(hi));
        ((short*)(wsd + W2FHI_OFF_D))[i] = (short)hi;
        ((short*)(wsd + W2FLO_OFF_D))[i] = (short)lo;
    }
    if (i >= NWCONV) return;
    float v;
    if      (i < B1D_OFF) v = w1[i];
    else if (i < W2D_OFF) v = b1[i - B1D_OFF];
    else if (i < B2D_OFF) v = w2[i - W2D_OFF];
    else if (i < W3D_OFF) v = b2[i - B2D_OFF];
    else if (i < B3D_OFF) v = w3[i - W3D_OFF];
    else                  v = b3[0];
    wsd[i] = (double)v;
}

// ---------------------------------------------------------------------------
// Kernel 1: P[n][j] = sum_k f[n][k] w1[k][j] (sel=0), Q with rows 128..255.
// fp64 accumulate; also writes fp32 copies for the fast pass. (unchanged)
// ---------------------------------------------------------------------------
__global__ __launch_bounds__(512, 4)
void pq_kernel(const float* __restrict__ features,
               const double* __restrict__ wsd,
               double* __restrict__ P,
               double* __restrict__ Q,
               float* __restrict__ P32,
               float* __restrict__ Q32) {
    __shared__ float fts[64 * 132];
    const int t  = threadIdx.x;
    const int n0 = blockIdx.x * 64;
    const int sel = blockIdx.y;

    {
        const int n = t & 63, q = t >> 6;
        const int gn = n0 + n;
        #pragma unroll
        for (int i = 0; i < 4; ++i) {
            const int k = q * 16 + i * 4;
            float4 f = make_float4(0.f, 0.f, 0.f, 0.f);
            if (gn < N_NODES) f = *(const float4*)(features + (size_t)gn * HID + k);
            *(float4*)(&fts[n * 132 + k]) = f;
        }
    }
    __syncthreads();

    const int l  = t & 63;
    const int wv = __builtin_amdgcn_readfirstlane(t >> 6);
    const int j0 = wv * 16;
    const double* wb = wsd + W1D_OFF + (size_t)(sel * 128) * HID + j0;

    double acc[16];
    #pragma unroll
    for (int c = 0; c < 16; ++c) acc[c] = 0.0;

    const float* frow = &fts[l * 132];
    for (int k = 0; k < 128; k += 4) {
        float4 f = *(const float4*)(frow + k);
        #pragma unroll
        for (int kk = 0; kk < 4; ++kk) {
            const double fv = (double)((&f.x)[kk]);
            const double* wr = wb + (size_t)(k + kk) * HID;   // uniform -> s_load
            #pragma unroll
            for (int c = 0; c < 16; ++c)
                acc[c] = fma(fv, wr[c], acc[c]);
        }
    }

    const int gn = n0 + l;
    if (gn < N_NODES) {
        double* dst = (sel ? Q : P) + (size_t)gn * HID + j0;
        #pragma unroll
        for (int c = 0; c < 16; c += 2)
            *(double2*)(dst + c) = make_double2(acc[c], acc[c + 1]);
        float* dstf = (sel ? Q32 : P32) + (size_t)gn * HID + j0;
        #pragma unroll
        for (int c = 0; c < 16; c += 4)
            *(float4*)(dstf + c) = make_float4((float)acc[c], (float)acc[c + 1],
                                               (float)acc[c + 2], (float)acc[c + 3]);
    }
}

// ---------------------------------------------------------------------------
// Kernel 2 (pass A): layer-1 fp32 -> h1 bf16 hi/lo (swizzled LDS) -> layer-2
// bf16x3 MFMA (32x32x16) with COALESCED frag-order W2 loads -> layer-3 via
// LDS transpose (swizzled vals[64][128], serial per-thread sums; replaces the
// 80-bpermute shuffle tree) -> exact-order z = fp64 sum of 8 fp32 quarters.
// ---------------------------------------------------------------------------
__global__ __launch_bounds__(512, 4)
void edgeA_kernel(const int*   __restrict__ indices,
                  const float* __restrict__ values,
                  const float* __restrict__ P32,
                  const float* __restrict__ Q32,
                  const float* __restrict__ w1,
                  const float* __restrict__ b1,
                  const short* __restrict__ w2fhi,
                  const short* __restrict__ w2flo,
                  const float* __restrict__ b2,
                  const float* __restrict__ w3,
                  const float* __restrict__ b3,
                  double* __restrict__ zbuf) {
    __shared__ __align__(16) char smemA[32768];  // h1hi 16KB | h1lo 16KB ; later vals[64][128] f32
    __shared__ float zpartS[8][64];              // per-quarter layer-3 partials
    short* h1hiB = (short*)smemA;                // base pointers (byte-offset addressed)
    float* vals  = (float*)smemA;

    const int t  = threadIdx.x;
    const int e0 = blockIdx.x * 64;

    // ---- stage h1: fp32 layer-1, split to bf16 hi/lo, swizzled LDS ----
    {
        const int e = t & 63, q = t >> 6;
        const int ge  = e0 + e;
        const int row = indices[ge];
        const int col = indices[NEDGE + ge];
        const float v = values[ge];
        const float* prow = P32 + (size_t)row * HID + q * 16;
        const float* qrow = Q32 + (size_t)col * HID + q * 16;
        const float* w1c  = w1 + (size_t)256 * HID + q * 16;  // uniform -> s_load
        const float* b1f  = b1 + q * 16;
        float h[16];
        #pragma unroll
        for (int i = 0; i < 16; i += 4) {
            float4 p  = *(const float4*)(prow + i);
            float4 qq = *(const float4*)(qrow + i);
            h[i]     = fmaxf(fmaf(v, w1c[i],     p.x + qq.x) + b1f[i],     0.f);
            h[i + 1] = fmaxf(fmaf(v, w1c[i + 1], p.y + qq.y) + b1f[i + 1], 0.f);
            h[i + 2] = fmaxf(fmaf(v, w1c[i + 2], p.z + qq.z) + b1f[i + 2], 0.f);
            h[i + 3] = fmaxf(fmaf(v, w1c[i + 3], p.w + qq.w) + b1f[i + 3], 0.f);
        }
        union { short s[8]; short8 v8; } H0, H1, L0, L1;
        #pragma unroll
        for (int i = 0; i < 8; ++i) {
            const unsigned short hiA = f2bf(h[i]);
            H0.s[i] = (short)hiA;
            L0.s[i] = (short)f2bf(h[i] - bf2f(hiA));
            const unsigned short hiB = f2bf(h[i + 8]);
            H1.s[i] = (short)hiB;
            L1.s[i] = (short)f2bf(h[i + 8] - bf2f(hiB));
        }
        // row = 256 B; XOR-swizzle 16B granules: byte ^= (e&7)<<4 (G4 fix)
        const int a0 = (e * 256 + q * 32) ^ ((e & 7) << 4);
        *(short8*)(smemA + a0)                = H0.v8;
        *(short8*)(smemA + (a0 ^ 16))         = H1.v8;
        *(short8*)(smemA + 16384 + a0)        = L0.v8;
        *(short8*)(smemA + 16384 + (a0 ^ 16)) = L1.v8;
    }
    __syncthreads();

    // ---- layer-2: bf16x3 MFMA, one 32x32 tile per wave, K = 8x16 ----
    const int l  = t & 63;
    const int wv = __builtin_amdgcn_readfirstlane(t >> 6);
    const int jt = wv & 3, et = wv >> 2;
    const int jj = jt * 32 + (l & 31);           // this lane's output column j
    // frag-order W2: lane-consecutive 16B -> coalesced 1KB per load instr
    const short* w2h_l = w2fhi + (size_t)(jt * 64 + l) * 8;
    const short* w2l_l = w2flo + (size_t)(jt * 64 + l) * 8;

    f32x16 acc;
    #pragma unroll
    for (int r = 0; r < 16; ++r) acc[r] = 0.f;
    const int eA    = et * 32 + (l & 31);        // A row = edge
    const int abase = eA * 256;
    const int aswz  = (eA & 7) << 4;
    const int ah    = (l >> 5) * 16;
    #pragma unroll 2
    for (int s = 0; s < 8; ++s) {
        const int ao = (abase + s * 32 + ah) ^ aswz;
        const short8 ahi = *(const short8*)(smemA + ao);
        const short8 alo = *(const short8*)(smemA + 16384 + ao);
        const short8 bh  = *(const short8*)(w2h_l + s * 2048);   // (s*4+jt)*64*8
        const short8 bl  = *(const short8*)(w2l_l + s * 2048);
        acc = __builtin_amdgcn_mfma_f32_32x32x16_bf16(ahi, bh, acc, 0, 0, 0);
        acc = __builtin_amdgcn_mfma_f32_32x32x16_bf16(alo, bh, acc, 0, 0, 0);
        acc = __builtin_amdgcn_mfma_f32_32x32x16_bf16(ahi, bl, acc, 0, 0, 0);
    }
    __syncthreads();   // all waves done reading h1 -> safe to overwrite as vals

    // ---- layer-3 part 1: write relu(acc+b2)*w3 to swizzled vals[64][128] ----
    // C/D map: col = l&31 (=j within tile), row(edge) = (r&3)+8*(r>>2)+4*(l>>5)
    // swizzle: 16B granule g' = (j>>2) ^ ((e&7)<<2)  (breaks stride-512B banks)
    {
        const float b2j = b2[jj];
        const float w3j = w3[jj];
        #pragma unroll
        for (int r = 0; r < 16; ++r) {
            const int e_loc = (r & 3) + 8 * (r >> 2) + 4 * (l >> 5);
            const int e = et * 32 + e_loc;
            const int g = (jj >> 2) ^ ((e & 7) << 2);
            vals[e * 128 + g * 4 + (jj & 3)] = fmaxf(acc[r] + b2j, 0.f) * w3j;
        }
    }
    __syncthreads();

    // ---- layer-3 part 2: per-thread serial sum of 16 j's (one quarter) ----
    {
        const int e = t & 63, q = t >> 6;
        float sq = 0.f;
        #pragma unroll
        for (int i = 0; i < 4; ++i) {
            const int g = (q * 4 + i) ^ ((e & 7) << 2);
            const float4 v4 = *(const float4*)(vals + e * 128 + g * 4);
            sq += v4.x; sq += v4.y; sq += v4.z; sq += v4.w;    // ascending j
        }
        zpartS[q][e] = sq;
    }
    __syncthreads();

    // ---- exact z: ordered fp64 sum of the 8 fp32 quarter partials ----
    if (t < 64) {
        double z = (double)b3[0];
        #pragma unroll
        for (int q = 0; q < 8; ++q) z += (double)zpartS[q][t];
        zbuf[e0 + t] = z;
    }
}

// ---------------------------------------------------------------------------
// Kernel 2b: fp64 epilogue over all edges (1 thread/edge, 16-lane groups).
// Writes out; flags near-boundary nodes for fp64 repair. (unchanged)
// ---------------------------------------------------------------------------
__global__ __launch_bounds__(256, 8)
void epi_kernel(const double* __restrict__ zbuf,
                const float*  __restrict__ tempr,
                int*          __restrict__ fcnt,
                int*          __restrict__ flist,
                float*        __restrict__ out) {
    const int t  = threadIdx.x;
    const int ge = blockIdx.x * 256 + t;
    const int lane = t & 63;
    const int base = lane & 48;

    const double z = zbuf[ge];
    const double T = (double)tempr[0];

    double m = z;
    #pragma unroll
    for (int d = 1; d < 16; d <<= 1) m = fmax(m, __shfl_xor(m, d));
    const double e1 = exp(z - m);
    double s = 0.0;
    #pragma unroll
    for (int k = 0; k < 16; ++k) s += __shfl(e1, base + k);
    const double pi = e1 / s;

    const double x  = log(pi + 1e-8) / T;
    double hard = 1.0 / (1.0 + exp(-x));
    hard = fmin(fmax(hard, 0.0), 1.0);

    double m2 = hard;
    #pragma unroll
    for (int d = 1; d < 16; d <<= 1) m2 = fmax(m2, __shfl_xor(m2, d));
    const double e2 = exp(hard - m2);
    double s2 = 0.0;
    #pragma unroll
    for (int k = 0; k < 16; ++k) s2 += __shfl(e2, base + k);
    const double y = e2 / s2;

    int cgt = 0, ceq = 0;
    #pragma unroll
    for (int j = 0; j < 16; ++j) {
        const double yj = __shfl(y, base + j);
        cgt += (yj > y);
        ceq += (yj == y);
    }
    double cand = (cgt <= 7 && cgt + ceq >= 8) ? y : -1.0e300;
    double thre = cand;
    #pragma unroll
    for (int d = 1; d < 16; d <<= 1) thre = fmax(thre, __shfl_xor(thre, d));

    const double g = (y - thre) + 1e-7;
    out[ge] = (g > 0.0) ? (float)y : 0.0f;

    const bool near = (y != thre) && (fabs(g) < TAU);
    const unsigned long long ball = __ballot(near);
    if ((lane & 15) == 0) {
        if ((ball >> base) & 0xFFFFull) {
            const int nid = ge >> 4;
            const int idx = atomicAdd(fcnt, 1);
            flist[idx] = nid;
        }
    }
}

// ---------------------------------------------------------------------------
// Kernel 3 (pass B): exact fp64 pipeline for flagged nodes only. (unchanged)
// ---------------------------------------------------------------------------
__global__ __launch_bounds__(512, 4)
void edgeB_kernel(const int*   __restrict__ indices,
                  const float* __restrict__ values,
                  const float* __restrict__ tempr,
                  const double* __restrict__ wsd,
                  const double* __restrict__ P,
                  const double* __restrict__ Q,
                  const int*   __restrict__ fcnt,
                  const int*   __restrict__ flist,
                  float* __restrict__ out) {
    __shared__ double h1s[64 * LDSP];
    __shared__ double zpart[8][64];
    __shared__ int nids[4];
    const int t = threadIdx.x;
    const int cnt = *fcnt;

    for (int g0 = blockIdx.x * 4; g0 < cnt; g0 += gridDim.x * 4) {
        if (t < 4) nids[t] = (g0 + t < cnt) ? flist[g0 + t] : -1;
        __syncthreads();

        {
            const int e = t & 63, q = t >> 6;
            const int node = nids[e >> 4];
            double* hdst = &h1s[e * LDSP + q * 16];
            if (node >= 0) {
                const int ge = node * 16 + (e & 15);
                const int row = indices[ge];
                const int col = indices[NEDGE + ge];
                const double v = (double)values[ge];
                const double* prow = P + (size_t)row * HID + q * 16;
                const double* qrow = Q + (size_t)col * HID + q * 16;
                const double* w1c  = wsd + W1D_OFF + (size_t)256 * HID + q * 16;
                const double* b1d  = wsd + B1D_OFF + q * 16;
                #pragma unroll
                for (int i = 0; i < 16; i += 2) {
                    double2 p  = *(const double2*)(prow + i);
                    double2 qq = *(const double2*)(qrow + i);
                    hdst[i]     = fmax(fma(v, w1c[i],     p.x + qq.x) + b1d[i],     0.0);
                    hdst[i + 1] = fmax(fma(v, w1c[i + 1], p.y + qq.y) + b1d[i + 1], 0.0);
                }
            } else {
                #pragma unroll
                for (int i = 0; i < 16; ++i) hdst[i] = 0.0;
            }
        }
        __syncthreads();

        const int l  = t & 63;
        const int wv = __builtin_amdgcn_readfirstlane(t >> 6);
        const int j0 = wv * 16;
        const double* w2b = wsd + W2D_OFF + j0;

        double acc[16];
        #pragma unroll
        for (int c = 0; c < 16; ++c) acc[c] = 0.0;

        const double* hrow = &h1s[l * LDSP];
        for (int k = 0; k < 128; k += 2) {
            const double h0  = hrow[k];
            const double h1v = hrow[k + 1];
            const double* wr0 = w2b + (size_t)k * HID;
            const double* wr1 = wr0 + HID;
            #pragma unroll
            for (int c = 0; c < 16; ++c) acc[c] = fma(h0,  wr0[c], acc[c]);
            #pragma unroll
            for (int c = 0; c < 16; ++c) acc[c] = fma(h1v, wr1[c], acc[c]);
        }

        {
            const double* b2d = wsd + B2D_OFF + j0;
            const double* w3d = wsd + W3D_OFF + j0;
            double part = 0.0;
            #pragma unroll
            for (int c = 0; c < 16; ++c) {
                const double h2 = fmax(acc[c] + b2d[c], 0.0);
                part = fma(h2, w3d[c], part);
            }
            zpart[wv][l] = part;
        }
        __syncthreads();

        if (t < 64) {
            double z = wsd[B3D_OFF];
            #pragma unroll
            for (int w = 0; w < 8; ++w) z += zpart[w][t];

            const double T = (double)tempr[0];
            const int base = t & 48;

            double m = z;
            #pragma unroll
            for (int d = 1; d < 16; d <<= 1) m = fmax(m, __shfl_xor(m, d));
            const double e1 = exp(z - m);
            double s = 0.0;
            #pragma unroll
            for (int k = 0; k < 16; ++k) s += __shfl(e1, base + k);
            const double pi = e1 / s;

            const double x  = log(pi + 1e-8) / T;
            double hard = 1.0 / (1.0 + exp(-x));
            hard = fmin(fmax(hard, 0.0), 1.0);

            double m2 = hard;
            #pragma unroll
            for (int d = 1; d < 16; d <<= 1) m2 = fmax(m2, __shfl_xor(m2, d));
            const double e2 = exp(hard - m2);
            double s2 = 0.0;
            #pragma unroll
            for (int k = 0; k < 16; ++k) s2 += __shfl(e2, base + k);
            const double y = e2 / s2;

            int cgt = 0, ceq = 0;
            #pragma unroll
            for (int j = 0; j < 16; ++j) {
                const double yj = __shfl(y, base + j);
                cgt += (yj > y);
                ceq += (yj == y);
            }
            double cand = (cgt <= 7 && cgt + ceq >= 8) ? y : -1.0e300;
            double thre = cand;
            #pragma unroll
            for (int d = 1; d < 16; d <<= 1) thre = fmax(thre, __shfl_xor(thre, d));

            const double g = (y - thre) + 1e-7;
            const int node = nids[t >> 4];
            if (node >= 0)
                out[node * 16 + (t & 15)] = (g > 0.0) ? (float)y : 0.0f;
        }
        __syncthreads();
    }
}

// ---------------------------------------------------------------------------
extern "C" void kernel_launch(void* const* d_in, const int* in_sizes, int n_in,
                              void* d_out, int out_size, void* d_ws, size_t ws_size,
                              hipStream_t stream) {
    const float* features = (const float*)d_in[0];
    const int*   indices  = (const int*)  d_in[1];
    const float* values   = (const float*)d_in[2];
    const float* tempr    = (const float*)d_in[3];
    const float* w1       = (const float*)d_in[4];
    const float* b1       = (const float*)d_in[5];
    const float* w2       = (const float*)d_in[6];
    const float* b2       = (const float*)d_in[7];
    const float* w3       = (const float*)d_in[8];
    const float* b3       = (const float*)d_in[9];
    float* out = (float*)d_out;

    double* wsd = (double*)d_ws;
    double* P64 = wsd + PQ64_OFF;
    double* Q64 = P64 + (size_t)N_NODES * HID;
    float*  P32 = (float*)(wsd + P32_OFF_D);
    float*  Q32 = P32 + (size_t)N_NODES * HID;
    int*    fcnt  = (int*)(wsd + FLAG_OFF_D);
    int*    flist = fcnt + 1;
    double* zbuf  = wsd + Z_OFF_D;
    const short* w2fhi = (const short*)(wsd + W2FHI_OFF_D);
    const short* w2flo = (const short*)(wsd + W2FLO_OFF_D);

    conv_kernel<<<(NWCONV + 255) / 256, 256, 0, stream>>>(w1, b1, w2, b2, w3, b3, wsd);

    dim3 g1((N_NODES + 63) / 64, 2);
    pq_kernel<<<g1, 512, 0, stream>>>(features, wsd, P64, Q64, P32, Q32);

    edgeA_kernel<<<NEDGE / 64, 512, 0, stream>>>(indices, values, P32, Q32,
                                                 w1, b1, w2fhi, w2flo, b2, w3, b3, zbuf);

    epi_kernel<<<NEDGE / 256, 256, 0, stream>>>(zbuf, tempr, fcnt, flist, out);

    edgeB_kernel<<<512, 512, 0, stream>>>(indices, values, tempr, wsd, P64, Q64,
                                          fcnt, flist, out);
}